// Round 1
// baseline (1106.956 us; speedup 1.0000x reference)
//
#include <hip/hip_runtime.h>
#include <stdint.h>
#include <math.h>

typedef unsigned short u16;
typedef short s16x8 __attribute__((ext_vector_type(8)));
typedef float f32x4 __attribute__((ext_vector_type(4)));
typedef u16 u16x4 __attribute__((ext_vector_type(4)));

#define FDIM 512
#define F2 1024
#define BATCH 16384
#define NST 6

// round-to-nearest-even fp32 -> bf16 bits
__device__ __forceinline__ u16 f2bf(float f) {
  uint32_t u = __float_as_uint(f);
  u += 0x7FFFu + ((u >> 16) & 1u);
  return (u16)(u >> 16);
}

__device__ __forceinline__ void ld_lds16(u16* lds, const u16* g) {
  __builtin_amdgcn_global_load_lds(
      (const __attribute__((address_space(1))) uint32_t*)g,
      (__attribute__((address_space(3))) uint32_t*)lds, 16, 0, 0);
}

// ---------------- entmax 1.5 over each of the 6 mask rows (512 elems) -------
__global__ __launch_bounds__(512) void entmax_kernel(const float* __restrict__ masks,
                                                     float* __restrict__ fm) {
  __shared__ float sx[FDIM];    // x values (original order)
  __shared__ float ssort[FDIM]; // sorted descending
  __shared__ float stau[FDIM];  // tau (also used as max-reduce scratch)
  __shared__ int ssup;
  const int d = blockIdx.x;
  const int j = threadIdx.x;
  float v = masks[d * FDIM + j];

  // max reduce (tree in stau)
  stau[j] = v;
  __syncthreads();
  for (int s = 256; s > 0; s >>= 1) {
    if (j < s) stau[j] = fmaxf(stau[j], stau[j + s]);
    __syncthreads();
  }
  float mx = stau[0];
  __syncthreads();

  float xx = (v - mx) * 0.5f;
  sx[j] = xx;
  __syncthreads();

  // rank by counting (descending, index tiebreak) -> scatter into ssort
  int r = 0;
  for (int i = 0; i < FDIM; i++) {
    float xi = sx[i];
    r += (xi > xx) || (xi == xx && i < j);
  }
  ssort[r] = xx;
  __syncthreads();

  if (j == 0) {
    float s = 0.f, s2 = 0.f;
    for (int i = 0; i < FDIM; i++) {
      float t = ssort[i];
      s += t;
      s2 += t * t;
      float rho = (float)(i + 1);
      float mean = s / rho;
      float msq = s2 / rho;
      float ss = rho * (msq - mean * mean);
      float delta = (1.f - ss) / rho;
      if (delta < 0.f) delta = 0.f;
      stau[i] = mean - sqrtf(delta);
    }
    ssup = 0;
  }
  __syncthreads();
  if (stau[j] <= ssort[j]) atomicAdd(&ssup, 1);
  __syncthreads();
  float tstar = stau[ssup - 1];
  float c = fmaxf(xx - tstar, 0.f);
  fm[d * FDIM + j] = c * c;
}

// ---------------- fp32 -> bf16 weight conversion ----------------------------
__global__ __launch_bounds__(256) void cvt_kernel(const float* __restrict__ src,
                                                  u16* __restrict__ dst, int n4) {
  int t = blockIdx.x * blockDim.x + threadIdx.x;
  if (t >= n4) return;
  float4 v = *(const float4*)(src + (size_t)t * 4);
  u16x4 o = {f2bf(v.x), f2bf(v.y), f2bf(v.z), f2bf(v.w)};
  *(u16x4*)(dst + (size_t)t * 4) = o;
}

// ---------------- A1 = [fm*x , h] in bf16 -----------------------------------
__global__ __launch_bounds__(256) void build_a1_kernel(const float* __restrict__ x,
                                                       const float* __restrict__ h,
                                                       const float* __restrict__ fm,
                                                       u16* __restrict__ A1) {
  int t = blockIdx.x * blockDim.x + threadIdx.x;  // BATCH*128 threads
  int m = t >> 7;
  int c = (t & 127) << 2;
  float4 xv = *(const float4*)(x + (size_t)m * FDIM + c);
  float4 fv = *(const float4*)(fm + c);
  u16x4 o1 = {f2bf(xv.x * fv.x), f2bf(xv.y * fv.y), f2bf(xv.z * fv.z), f2bf(xv.w * fv.w)};
  *(u16x4*)(A1 + (size_t)m * F2 + c) = o1;
  float4 hv = *(const float4*)(h + (size_t)m * FDIM + c);
  u16x4 o2 = {f2bf(hv.x), f2bf(hv.y), f2bf(hv.z), f2bf(hv.w)};
  *(u16x4*)(A1 + (size_t)m * F2 + FDIM + c) = o2;
}

// ---------------- A2 right half = bf16(x) (once per call) -------------------
__global__ __launch_bounds__(256) void fill_a2x_kernel(const float* __restrict__ x,
                                                       u16* __restrict__ A2) {
  int t = blockIdx.x * blockDim.x + threadIdx.x;
  int m = t >> 7;
  int c = (t & 127) << 2;
  float4 xv = *(const float4*)(x + (size_t)m * FDIM + c);
  u16x4 o = {f2bf(xv.x), f2bf(xv.y), f2bf(xv.z), f2bf(xv.w)};
  *(u16x4*)(A2 + (size_t)m * F2 + FDIM + c) = o;
}

// ---------------- shared GEMM core: C[128x128] = A[128xK] * B[NxK]^T --------
// A,B are bf16 K-major. 256 threads = 4 waves in 2x2; each wave 64x64 via
// 4x4 fragments of 16x16x32 MFMA. LDS tiles [128][32], staged by
// global_load_lds (16B/lane, linear layout).
__device__ __forceinline__ void gemm_core(const u16* __restrict__ Ag,
                                          const u16* __restrict__ Bg, int K,
                                          int m0, int n0, f32x4 acc[4][4],
                                          u16* sA, u16* sB) {
  const int tid = threadIdx.x;
  const int lane = tid & 63;
  const int wid = tid >> 6;
  const int wr = (wid >> 1) << 6;
  const int wc = (wid & 1) << 6;

  const int srow = tid >> 2;        // 0..63
  const int scol = (tid & 3) << 3;  // 0,8,16,24 (bf16 elems)

  const u16* ga0 = Ag + (size_t)(m0 + srow) * K + scol;
  const u16* ga1 = ga0 + (size_t)64 * K;
  const u16* gb0 = Bg + (size_t)(n0 + srow) * K + scol;
  const u16* gb1 = gb0 + (size_t)64 * K;
  u16* la0 = sA + srow * 32 + scol;
  u16* la1 = la0 + 64 * 32;
  u16* lb0 = sB + srow * 32 + scol;
  u16* lb1 = lb0 + 64 * 32;

  const int fr = lane & 15;
  const int fk = (lane >> 4) << 3;

#pragma unroll
  for (int i = 0; i < 4; i++)
#pragma unroll
    for (int j = 0; j < 4; j++) acc[i][j] = (f32x4){0.f, 0.f, 0.f, 0.f};

  for (int k0 = 0; k0 < K; k0 += 32) {
    ld_lds16(la0, ga0 + k0);
    ld_lds16(la1, ga1 + k0);
    ld_lds16(lb0, gb0 + k0);
    ld_lds16(lb1, gb1 + k0);
    __syncthreads();  // drains vmcnt -> LDS tiles valid

    s16x8 af[4], bf[4];
#pragma unroll
    for (int i = 0; i < 4; i++) {
      af[i] = *(const s16x8*)(sA + (wr + i * 16 + fr) * 32 + fk);
      bf[i] = *(const s16x8*)(sB + (wc + i * 16 + fr) * 32 + fk);
    }
#pragma unroll
    for (int i = 0; i < 4; i++)
#pragma unroll
      for (int j = 0; j < 4; j++)
        acc[i][j] = __builtin_amdgcn_mfma_f32_16x16x32_bf16(af[i], bf[j], acc[i][j], 0, 0, 0);
    __syncthreads();  // protect LDS before next stage overwrites
  }
}

// ---------------- GEMM1: h_in = A1 @ W1^T + b1; z->zbuf, r*h->A2 ------------
__global__ __launch_bounds__(256) void gemm1_kernel(const u16* __restrict__ A1,
                                                    const u16* __restrict__ W1,
                                                    const float* __restrict__ b1,
                                                    const float* __restrict__ hcur,
                                                    float* __restrict__ zbuf,
                                                    u16* __restrict__ A2) {
  __shared__ u16 sA[128 * 32];
  __shared__ u16 sB[128 * 32];
  const int bx = blockIdx.x;
  const int m0 = (bx >> 3) << 7;  // N/128 = 8
  const int n0 = (bx & 7) << 7;
  f32x4 acc[4][4];
  gemm_core(A1, W1, F2, m0, n0, acc, sA, sB);

  const int tid = threadIdx.x;
  const int lane = tid & 63;
  const int wid = tid >> 6;
  const int wr = (wid >> 1) << 6;
  const int wc = (wid & 1) << 6;
  const int fcol = lane & 15;
  const int frow = (lane >> 4) << 2;

#pragma unroll
  for (int i = 0; i < 4; i++) {
#pragma unroll
    for (int j = 0; j < 4; j++) {
#pragma unroll
      for (int r = 0; r < 4; r++) {
        int gm = m0 + wr + i * 16 + frow + r;
        int gn = n0 + wc + j * 16 + fcol;
        float v = acc[i][j][r] + b1[gn];
        float s = 1.0f / (1.0f + expf(-v));
        if (gn < FDIM) {
          zbuf[(size_t)gm * FDIM + gn] = s;
        } else {
          int c = gn - FDIM;
          A2[(size_t)gm * F2 + c] = f2bf(s * hcur[(size_t)gm * FDIM + c]);
        }
      }
    }
  }
}

// ---------------- GEMM2: h_out = tanh(A2 @ W2^T + b2); gated update ---------
__global__ __launch_bounds__(256) void gemm2_kernel(const u16* __restrict__ A2,
                                                    const u16* __restrict__ W2,
                                                    const float* __restrict__ b2,
                                                    const float* __restrict__ zbuf,
                                                    const float* hcur,
                                                    float* hnext) {
  __shared__ u16 sA[128 * 32];
  __shared__ u16 sB[128 * 32];
  const int bx = blockIdx.x;
  const int m0 = (bx >> 2) << 7;  // N/128 = 4
  const int n0 = (bx & 3) << 7;
  f32x4 acc[4][4];
  gemm_core(A2, W2, F2, m0, n0, acc, sA, sB);

  const int tid = threadIdx.x;
  const int lane = tid & 63;
  const int wid = tid >> 6;
  const int wr = (wid >> 1) << 6;
  const int wc = (wid & 1) << 6;
  const int fcol = lane & 15;
  const int frow = (lane >> 4) << 2;

#pragma unroll
  for (int i = 0; i < 4; i++) {
#pragma unroll
    for (int j = 0; j < 4; j++) {
#pragma unroll
      for (int r = 0; r < 4; r++) {
        int gm = m0 + wr + i * 16 + frow + r;
        int gn = n0 + wc + j * 16 + fcol;
        float v = acc[i][j][r] + b2[gn];
        float ho = tanhf(v);
        size_t idx = (size_t)gm * FDIM + gn;
        float z = zbuf[idx];
        float hv = hcur[idx];
        hnext[idx] = (1.0f - z) * hv + z * ho;
      }
    }
  }
}

extern "C" void kernel_launch(void* const* d_in, const int* in_sizes, int n_in,
                              void* d_out, int out_size, void* d_ws, size_t ws_size,
                              hipStream_t stream) {
  (void)in_sizes; (void)n_in; (void)out_size; (void)ws_size;
  const float* x = (const float*)d_in[0];
  const float* masks = (const float*)d_in[1];
  const float* W1f = (const float*)d_in[2];
  const float* b1 = (const float*)d_in[3];
  const float* W2f = (const float*)d_in[4];
  const float* b2 = (const float*)d_in[5];

  char* ws = (char*)d_ws;
  float* fm = (float*)ws;          ws += (size_t)NST * FDIM * 4;      // 12 KB
  u16* W1b = (u16*)ws;             ws += (size_t)NST * F2 * F2 * 2;   // 12.6 MB
  u16* W2b = (u16*)ws;             ws += (size_t)NST * FDIM * F2 * 2; // 6.3 MB
  u16* A1 = (u16*)ws;              ws += (size_t)BATCH * F2 * 2;      // 33.6 MB
  u16* A2 = (u16*)ws;              ws += (size_t)BATCH * F2 * 2;      // 33.6 MB
  float* zbuf = (float*)ws;        ws += (size_t)BATCH * FDIM * 4;    // 33.6 MB
  float* hbuf = (float*)ws;        ws += (size_t)BATCH * FDIM * 4;    // 33.6 MB
  float* out = (float*)d_out;

  entmax_kernel<<<NST, 512, 0, stream>>>(masks, fm);
  {
    int n4 = NST * F2 * F2 / 4;
    cvt_kernel<<<(n4 + 255) / 256, 256, 0, stream>>>(W1f, W1b, n4);
  }
  {
    int n4 = NST * FDIM * F2 / 4;
    cvt_kernel<<<(n4 + 255) / 256, 256, 0, stream>>>(W2f, W2b, n4);
  }
  fill_a2x_kernel<<<BATCH * 128 / 256, 256, 0, stream>>>(x, A2);

  for (int d = 0; d < NST; d++) {
    const float* hcur = (d == 0) ? x : hbuf;
    float* hnext = (d == NST - 1) ? out : hbuf;
    build_a1_kernel<<<BATCH * 128 / 256, 256, 0, stream>>>(x, hcur, fm + d * FDIM, A1);
    gemm1_kernel<<<(BATCH / 128) * (F2 / 128), 256, 0, stream>>>(
        A1, W1b + (size_t)d * F2 * F2, b1 + d * F2, hcur, zbuf, A2);
    gemm2_kernel<<<(BATCH / 128) * (FDIM / 128), 256, 0, stream>>>(
        A2, W2b + (size_t)d * FDIM * F2, b2 + d * FDIM, zbuf, hcur, hnext);
  }
}

// Round 2
// 978.605 us; speedup vs baseline: 1.1312x; 1.1312x over previous
//
#include <hip/hip_runtime.h>
#include <stdint.h>
#include <math.h>

typedef unsigned short u16;
typedef short s16x8 __attribute__((ext_vector_type(8)));
typedef float f32x4 __attribute__((ext_vector_type(4)));
typedef u16 u16x4 __attribute__((ext_vector_type(4)));

#define FDIM 512
#define F2 1024
#define BATCH 16384
#define NST 6

// round-to-nearest-even fp32 -> bf16 bits
__device__ __forceinline__ u16 f2bf(float f) {
  uint32_t u = __float_as_uint(f);
  u += 0x7FFFu + ((u >> 16) & 1u);
  return (u16)(u >> 16);
}

__device__ __forceinline__ void ld_lds16(u16* lds, const u16* g) {
  __builtin_amdgcn_global_load_lds(
      (const __attribute__((address_space(1))) uint32_t*)g,
      (__attribute__((address_space(3))) uint32_t*)lds, 16, 0, 0);
}

// ---------------- entmax 1.5 over each of the 6 mask rows (512 elems) -------
__global__ __launch_bounds__(512) void entmax_kernel(const float* __restrict__ masks,
                                                     float* __restrict__ fm) {
  __shared__ float sx[FDIM];
  __shared__ float ssort[FDIM];
  __shared__ float stau[FDIM];
  __shared__ int ssup;
  const int d = blockIdx.x;
  const int j = threadIdx.x;
  float v = masks[d * FDIM + j];

  stau[j] = v;
  __syncthreads();
  for (int s = 256; s > 0; s >>= 1) {
    if (j < s) stau[j] = fmaxf(stau[j], stau[j + s]);
    __syncthreads();
  }
  float mx = stau[0];
  __syncthreads();

  float xx = (v - mx) * 0.5f;
  sx[j] = xx;
  __syncthreads();

  int r = 0;
  for (int i = 0; i < FDIM; i++) {
    float xi = sx[i];
    r += (xi > xx) || (xi == xx && i < j);
  }
  ssort[r] = xx;
  __syncthreads();

  if (j == 0) {
    float s = 0.f, s2 = 0.f;
    for (int i = 0; i < FDIM; i++) {
      float t = ssort[i];
      s += t;
      s2 += t * t;
      float rho = (float)(i + 1);
      float mean = s / rho;
      float msq = s2 / rho;
      float ss = rho * (msq - mean * mean);
      float delta = (1.f - ss) / rho;
      if (delta < 0.f) delta = 0.f;
      stau[i] = mean - sqrtf(delta);
    }
    ssup = 0;
  }
  __syncthreads();
  if (stau[j] <= ssort[j]) atomicAdd(&ssup, 1);
  __syncthreads();
  float tstar = stau[ssup - 1];
  float c = fmaxf(xx - tstar, 0.f);
  fm[d * FDIM + j] = c * c;
}

// ---------------- W1 -> bf16, fm folded into first 512 cols -----------------
__global__ __launch_bounds__(256) void cvt_w1_kernel(const float* __restrict__ src,
                                                     const float* __restrict__ fm,
                                                     u16* __restrict__ dst) {
  int t = blockIdx.x * 256 + threadIdx.x;  // NST*F2*F2/4 threads
  int k = (t & 255) << 2;                  // col within row (F2/4=256)
  int dn = t >> 8;                         // d*F2 + n
  int d = dn >> 10;
  float4 v = *(const float4*)(src + (size_t)t * 4);
  if (k < FDIM) {
    float4 s = *(const float4*)(fm + (size_t)d * FDIM + k);
    v.x *= s.x; v.y *= s.y; v.z *= s.z; v.w *= s.w;
  }
  u16x4 o = {f2bf(v.x), f2bf(v.y), f2bf(v.z), f2bf(v.w)};
  *(u16x4*)(dst + (size_t)t * 4) = o;
}

// ---------------- plain fp32 -> bf16 (W2) -----------------------------------
__global__ __launch_bounds__(256) void cvt_kernel(const float* __restrict__ src,
                                                  u16* __restrict__ dst, int n4) {
  int t = blockIdx.x * blockDim.x + threadIdx.x;
  if (t >= n4) return;
  float4 v = *(const float4*)(src + (size_t)t * 4);
  u16x4 o = {f2bf(v.x), f2bf(v.y), f2bf(v.z), f2bf(v.w)};
  *(u16x4*)(dst + (size_t)t * 4) = o;
}

// ---------------- upfront: A1=[x_bf|x_bf], A2 right half = x_bf -------------
__global__ __launch_bounds__(256) void fill_xbf_kernel(const float* __restrict__ x,
                                                       u16* __restrict__ A1,
                                                       u16* __restrict__ A2) {
  int t = blockIdx.x * blockDim.x + threadIdx.x;  // BATCH*128 threads
  int m = t >> 7;
  int c = (t & 127) << 2;
  float4 xv = *(const float4*)(x + (size_t)m * FDIM + c);
  u16x4 o = {f2bf(xv.x), f2bf(xv.y), f2bf(xv.z), f2bf(xv.w)};
  *(u16x4*)(A1 + (size_t)m * F2 + c) = o;          // left: x (fm in weights)
  *(u16x4*)(A1 + (size_t)m * F2 + FDIM + c) = o;   // right: h=x at stage 0
  *(u16x4*)(A2 + (size_t)m * F2 + FDIM + c) = o;   // A2 right half: x
}

// ---------------- 2-phase pipelined GEMM core -------------------------------
// C[128x128] = A[128xK] * B[NxK]^T, bf16 K-major, 256 thr = 4 waves (2x2),
// 4x4 frags of 16x16x32 MFMA. LDS: double-buffered [128][32] tiles staged by
// global_load_lds (16B/lane, linear). STAGE(t+1) issued BEFORE compute(t);
// one barrier (full drain) per K-step.
__device__ __forceinline__ void gemm_core2(const u16* __restrict__ Ag,
                                           const u16* __restrict__ Bg, int K,
                                           int m0, int n0, f32x4 acc[4][4],
                                           u16* sA, u16* sB) {
  const int tid = threadIdx.x;
  const int lane = tid & 63;
  const int wid = tid >> 6;
  const int wr = (wid >> 1) << 6;
  const int wc = (wid & 1) << 6;
  const int srow = tid >> 2;        // 0..63
  const int scol = (tid & 3) << 3;  // 0,8,16,24

  const u16* ga0 = Ag + (size_t)(m0 + srow) * K + scol;
  const u16* ga1 = ga0 + (size_t)64 * K;
  const u16* gb0 = Bg + (size_t)(n0 + srow) * K + scol;
  const u16* gb1 = gb0 + (size_t)64 * K;
  const int loff = srow * 32 + scol;

  const int fr = lane & 15;
  const int fk = (lane >> 4) << 3;

#pragma unroll
  for (int i = 0; i < 4; i++)
#pragma unroll
    for (int j = 0; j < 4; j++) acc[i][j] = (f32x4){0.f, 0.f, 0.f, 0.f};

  const int nt = K >> 5;
  // prologue: stage tile 0 into buf 0
  ld_lds16(sA + loff, ga0);
  ld_lds16(sA + 2048 + loff, ga1);
  ld_lds16(sB + loff, gb0);
  ld_lds16(sB + 2048 + loff, gb1);
  __syncthreads();  // drains vmcnt(0): buf0 valid

  int cur = 0;
  for (int t = 0; t < nt; t++) {
    const int nxt = cur ^ 1;
    if (t + 1 < nt) {  // issue next-tile loads; they fly during compute
      const int k0 = (t + 1) << 5;
      ld_lds16(sA + nxt * 4096 + loff, ga0 + k0);
      ld_lds16(sA + nxt * 4096 + 2048 + loff, ga1 + k0);
      ld_lds16(sB + nxt * 4096 + loff, gb0 + k0);
      ld_lds16(sB + nxt * 4096 + 2048 + loff, gb1 + k0);
    }
    const u16* a = sA + cur * 4096;
    const u16* b = sB + cur * 4096;
    s16x8 af[4], bfr[4];
#pragma unroll
    for (int i = 0; i < 4; i++) {
      af[i] = *(const s16x8*)(a + (wr + i * 16 + fr) * 32 + fk);
      bfr[i] = *(const s16x8*)(b + (wc + i * 16 + fr) * 32 + fk);
    }
#pragma unroll
    for (int i = 0; i < 4; i++)
#pragma unroll
      for (int j = 0; j < 4; j++)
        acc[i][j] = __builtin_amdgcn_mfma_f32_16x16x32_bf16(af[i], bfr[j], acc[i][j], 0, 0, 0);
    __syncthreads();  // drains vmcnt+lgkm: next tile landed, reads done
    cur = nxt;
  }
}

// ---------------- GEMM1: h_in = A1 @ W1'^T + b1; z->zbuf, r*h->A2 -----------
__global__ __launch_bounds__(256) void gemm1_kernel(const u16* __restrict__ A1,
                                                    const u16* __restrict__ W1,
                                                    const float* __restrict__ b1,
                                                    const float* __restrict__ hcur,
                                                    float* __restrict__ zbuf,
                                                    u16* __restrict__ A2) {
  __shared__ u16 sA[2 * 4096];
  __shared__ u16 sB[2 * 4096];
  const int bx = blockIdx.x;
  const int wg = (bx & 7) * 128 + (bx >> 3);  // XCD swizzle, nwg=1024
  const int m0 = (wg >> 3) << 7;
  const int n0 = (wg & 7) << 7;
  f32x4 acc[4][4];
  gemm_core2(A1, W1, F2, m0, n0, acc, sA, sB);

  const int tid = threadIdx.x;
  const int lane = tid & 63;
  const int wid = tid >> 6;
  const int wr = (wid >> 1) << 6;
  const int wc = (wid & 1) << 6;
  const int fcol = lane & 15;
  const int frow = (lane >> 4) << 2;

#pragma unroll
  for (int i = 0; i < 4; i++) {
#pragma unroll
    for (int j = 0; j < 4; j++) {
#pragma unroll
      for (int r = 0; r < 4; r++) {
        int gm = m0 + wr + i * 16 + frow + r;
        int gn = n0 + wc + j * 16 + fcol;
        float v = acc[i][j][r] + b1[gn];
        float s = 1.0f / (1.0f + expf(-v));
        if (gn < FDIM) {
          zbuf[(size_t)gm * FDIM + gn] = s;
        } else {
          int c = gn - FDIM;
          A2[(size_t)gm * F2 + c] = f2bf(s * hcur[(size_t)gm * FDIM + c]);
        }
      }
    }
  }
}

// ---------------- GEMM2: h_out = tanh(A2 @ W2^T + b2); gated update ---------
// Also writes bf16(h_next) into A1 right half for the next stage.
__global__ __launch_bounds__(256) void gemm2_kernel(const u16* __restrict__ A2,
                                                    const u16* __restrict__ W2,
                                                    const float* __restrict__ b2,
                                                    const float* __restrict__ zbuf,
                                                    const float* hcur,
                                                    float* hnext,
                                                    u16* __restrict__ A1,
                                                    int write_a1) {
  __shared__ u16 sA[2 * 4096];
  __shared__ u16 sB[2 * 4096];
  const int bx = blockIdx.x;
  const int wg = (bx & 7) * 64 + (bx >> 3);  // XCD swizzle, nwg=512
  const int m0 = (wg >> 2) << 7;
  const int n0 = (wg & 3) << 7;
  f32x4 acc[4][4];
  gemm_core2(A2, W2, F2, m0, n0, acc, sA, sB);

  const int tid = threadIdx.x;
  const int lane = tid & 63;
  const int wid = tid >> 6;
  const int wr = (wid >> 1) << 6;
  const int wc = (wid & 1) << 6;
  const int fcol = lane & 15;
  const int frow = (lane >> 4) << 2;

#pragma unroll
  for (int i = 0; i < 4; i++) {
#pragma unroll
    for (int j = 0; j < 4; j++) {
#pragma unroll
      for (int r = 0; r < 4; r++) {
        int gm = m0 + wr + i * 16 + frow + r;
        int gn = n0 + wc + j * 16 + fcol;
        float v = acc[i][j][r] + b2[gn];
        float ho = tanhf(v);
        size_t idx = (size_t)gm * FDIM + gn;
        float z = zbuf[idx];
        float hv = hcur[idx];
        float hn = (1.0f - z) * hv + z * ho;
        hnext[idx] = hn;
        if (write_a1) A1[(size_t)gm * F2 + FDIM + gn] = f2bf(hn);
      }
    }
  }
}

extern "C" void kernel_launch(void* const* d_in, const int* in_sizes, int n_in,
                              void* d_out, int out_size, void* d_ws, size_t ws_size,
                              hipStream_t stream) {
  (void)in_sizes; (void)n_in; (void)out_size; (void)ws_size;
  const float* x = (const float*)d_in[0];
  const float* masks = (const float*)d_in[1];
  const float* W1f = (const float*)d_in[2];
  const float* b1 = (const float*)d_in[3];
  const float* W2f = (const float*)d_in[4];
  const float* b2 = (const float*)d_in[5];

  char* ws = (char*)d_ws;
  float* fm = (float*)ws;   ws += (size_t)NST * FDIM * 4;       // 12 KB
  u16* W1b = (u16*)ws;      ws += (size_t)NST * F2 * F2 * 2;    // 12.6 MB
  u16* W2b = (u16*)ws;      ws += (size_t)NST * FDIM * F2 * 2;  // 6.3 MB
  u16* A1 = (u16*)ws;       ws += (size_t)BATCH * F2 * 2;       // 33.6 MB
  u16* A2 = (u16*)ws;       ws += (size_t)BATCH * F2 * 2;       // 33.6 MB
  float* zbuf = (float*)ws; ws += (size_t)BATCH * FDIM * 4;     // 33.6 MB
  float* hbuf = (float*)ws; ws += (size_t)BATCH * FDIM * 4;     // 33.6 MB
  float* out = (float*)d_out;

  entmax_kernel<<<NST, 512, 0, stream>>>(masks, fm);
  cvt_w1_kernel<<<NST * F2 * F2 / 4 / 256, 256, 0, stream>>>(W1f, fm, W1b);
  {
    int n4 = NST * FDIM * F2 / 4;
    cvt_kernel<<<(n4 + 255) / 256, 256, 0, stream>>>(W2f, W2b, n4);
  }
  fill_xbf_kernel<<<BATCH * 128 / 256, 256, 0, stream>>>(x, A1, A2);

  for (int d = 0; d < NST; d++) {
    const float* hcur = (d == 0) ? x : hbuf;
    float* hnext = (d == NST - 1) ? out : hbuf;
    gemm1_kernel<<<(BATCH / 128) * (F2 / 128), 256, 0, stream>>>(
        A1, W1b + (size_t)d * F2 * F2, b1 + d * F2, hcur, zbuf, A2);
    gemm2_kernel<<<(BATCH / 128) * (FDIM / 128), 256, 0, stream>>>(
        A2, W2b + (size_t)d * FDIM * F2, b2 + d * FDIM, zbuf, hcur, hnext,
        A1, d < NST - 1);
  }
}